// Round 1
// baseline (4485.765 us; speedup 1.0000x reference)
//
#include <hip/hip_runtime.h>

#define NN 100000      // nodes
#define NE 1600000     // edges
#define NG 2048        // graphs
#define DH 128         // feature dim (D_IN = D_HID = D_EMB)

// selu(x) = 1.0507*x (x>0) else 1.0507*1.6733*expm1(x)
__device__ __forceinline__ float selu_f(float x) {
    return x > 0.f ? 1.0507009873554805f * x : 1.7580993408473766f * expm1f(x);
}

// degree count (with self-loop added later as +1)
__global__ __launch_bounds__(256) void k_deg(const int* __restrict__ dst, int* __restrict__ deg) {
    int e = blockIdx.x * 256 + threadIdx.x;
    if (e < NE) atomicAdd(deg + dst[e], 1);
}

__global__ __launch_bounds__(256) void k_dinv(const int* __restrict__ deg, float* __restrict__ dinv) {
    int i = blockIdx.x * 256 + threadIdx.x;
    if (i < NN) dinv[i] = rsqrtf((float)deg[i] + 1.0f);
}

// X = (affine(H) @ W) * dinv[row].  In-place safe (block reads only its own rows
// into LDS before any global write).  AFFINE applies previous layer's BN as
// per-channel scale/shift during LDS staging.
template<int AFFINE>
__global__ __launch_bounds__(256) void k_gemm(
    const float* __restrict__ H, const float* __restrict__ W,
    const float* __restrict__ sc, const float* __restrict__ sh,
    const float* __restrict__ dinv, float* __restrict__ X)
{
    __shared__ float hs[64][132];   // +4 pad: float4-aligned, bank-conflict-free
    __shared__ float ws[32][128];
    const int tid = threadIdx.x;
    const int base = blockIdx.x * 64;
    const int ct = tid & 15, rt = tid >> 4;
    const int r0 = rt * 4;
    const int cA = ct * 4, cB = cA + 64;

    #pragma unroll
    for (int i = 0; i < 8; ++i) {
        int idx4 = tid + i * 256;
        int r = idx4 >> 5;
        int c = (idx4 & 31) * 4;
        int row = base + r;
        float4 v = make_float4(0.f, 0.f, 0.f, 0.f);
        if (row < NN) v = *(const float4*)(H + (size_t)row * DH + c);
        if (AFFINE) {
            v.x = v.x * sc[c + 0] + sh[c + 0];
            v.y = v.y * sc[c + 1] + sh[c + 1];
            v.z = v.z * sc[c + 2] + sh[c + 2];
            v.w = v.w * sc[c + 3] + sh[c + 3];
        }
        *(float4*)&hs[r][c] = v;
    }

    float acc[4][8];
    #pragma unroll
    for (int i = 0; i < 4; ++i)
        #pragma unroll
        for (int j = 0; j < 8; ++j) acc[i][j] = 0.f;

    for (int kk = 0; kk < DH; kk += 32) {
        __syncthreads();
        #pragma unroll
        for (int i = 0; i < 4; ++i) {
            int idx4 = tid + i * 256;
            int k = idx4 >> 5;
            int c = (idx4 & 31) * 4;
            *(float4*)&ws[k][c] = *(const float4*)(W + (size_t)(kk + k) * DH + c);
        }
        __syncthreads();
        #pragma unroll
        for (int k = 0; k < 32; ++k) {
            float4 w0 = *(const float4*)&ws[k][cA];
            float4 w1 = *(const float4*)&ws[k][cB];
            #pragma unroll
            for (int i = 0; i < 4; ++i) {
                float h = hs[r0 + i][kk + k];
                acc[i][0] += h * w0.x; acc[i][1] += h * w0.y;
                acc[i][2] += h * w0.z; acc[i][3] += h * w0.w;
                acc[i][4] += h * w1.x; acc[i][5] += h * w1.y;
                acc[i][6] += h * w1.z; acc[i][7] += h * w1.w;
            }
        }
    }

    #pragma unroll
    for (int i = 0; i < 4; ++i) {
        int row = base + r0 + i;
        if (row < NN) {
            float di = dinv[row];
            float4 o0 = make_float4(acc[i][0] * di, acc[i][1] * di, acc[i][2] * di, acc[i][3] * di);
            float4 o1 = make_float4(acc[i][4] * di, acc[i][5] * di, acc[i][6] * di, acc[i][7] * di);
            *(float4*)(X + (size_t)row * DH + cA) = o0;
            *(float4*)(X + (size_t)row * DH + cB) = o1;
        }
    }
}

// Z[dst] += X[src] over all edges.  One wave per edge, 2 channels per lane.
__global__ __launch_bounds__(256) void k_edge(
    const float* __restrict__ X, const int* __restrict__ src,
    const int* __restrict__ dst, float* __restrict__ Z)
{
    int e = blockIdx.x * 4 + (threadIdx.x >> 6);
    if (e >= NE) return;
    int lane = threadIdx.x & 63;
    int s = src[e], d = dst[e];
    float2 v = *(const float2*)(X + (size_t)s * DH + lane * 2);
    unsafeAtomicAdd(Z + (size_t)d * DH + lane * 2, v.x);
    unsafeAtomicAdd(Z + (size_t)d * DH + lane * 2 + 1, v.y);
}

// y = selu(dinv[i]*(Z[i]+X[i]) + b[c]); Z <- y (in place).
// MODE 0: accumulate per-channel sum/sumsq (BN stats).  MODE 1: pool into hg.
template<int MODE>
__global__ __launch_bounds__(256) void k_post(
    const float* __restrict__ X, float* __restrict__ Z,
    const float* __restrict__ dinv, const float* __restrict__ bias,
    float* __restrict__ ssum, float* __restrict__ ssq,
    const int* __restrict__ batch, float* __restrict__ hg)
{
    const int tid = threadIdx.x;
    const int c = tid & 127;              // stride ≡ 0 mod 128 -> channel fixed
    const float bc = bias[c];
    float s = 0.f, s2 = 0.f;
    const int total = NN * DH;
    const int stride = gridDim.x * 256;
    for (int idx = blockIdx.x * 256 + tid; idx < total; idx += stride) {
        int i = idx >> 7;
        float val = dinv[i] * (Z[idx] + X[idx]) + bc;
        float y = selu_f(val);
        Z[idx] = y;
        if (MODE == 0) { s += y; s2 += y * y; }
        else unsafeAtomicAdd(hg + (size_t)batch[i] * DH + c, y);
    }
    if (MODE == 0) {
        __shared__ float r1[256], r2[256];
        r1[tid] = s; r2[tid] = s2;
        __syncthreads();
        if (tid < 128) {
            unsafeAtomicAdd(ssum + tid, r1[tid] + r1[tid + 128]);
            unsafeAtomicAdd(ssq + tid, r2[tid] + r2[tid + 128]);
        }
    }
}

// BN finalize: sc = g*rsqrt(var+eps), sh = be - mean*sc
__global__ void k_bnfin(const float* __restrict__ ssum, const float* __restrict__ ssq,
                        const float* __restrict__ gamma, const float* __restrict__ beta,
                        float* __restrict__ sc, float* __restrict__ sh)
{
    int c = threadIdx.x;
    float mean = ssum[c] * (1.f / NN);
    float var = ssq[c] * (1.f / NN) - mean * mean;
    float s = gamma[c] * rsqrtf(var + 1e-5f);
    sc[c] = s;
    sh[c] = beta[c] - mean * s;
}

// Final MLP: out[g] = selu(concat(hg, mol) @ Wf1 + bf1) @ Wf2 + bf2
__global__ __launch_bounds__(128) void k_mlp(
    const float* __restrict__ hg, const float* __restrict__ mol,
    const float* __restrict__ Wf1, const float* __restrict__ bf1,
    const float* __restrict__ Wf2, const float* __restrict__ bf2,
    float* __restrict__ out)
{
    int g = blockIdx.x, c = threadIdx.x;
    __shared__ float in_s[192];
    in_s[c] = hg[(size_t)g * DH + c];
    if (c < 64) in_s[128 + c] = mol[(size_t)g * 64 + c];
    __syncthreads();
    float acc = bf1[c];
    #pragma unroll 8
    for (int k = 0; k < 192; ++k) acc += in_s[k] * Wf1[k * DH + c];
    float h = selu_f(acc);
    float pv = h * Wf2[c];
    #pragma unroll
    for (int o = 32; o > 0; o >>= 1) pv += __shfl_down(pv, o);
    __shared__ float wsum[2];
    if ((c & 63) == 0) wsum[c >> 6] = pv;
    __syncthreads();
    if (c == 0) out[g] = wsum[0] + wsum[1] + bf2[0];
}

extern "C" void kernel_launch(void* const* d_in, const int* in_sizes, int n_in,
                              void* d_out, int out_size, void* d_ws, size_t ws_size,
                              hipStream_t stream)
{
    const float* x   = (const float*)d_in[0];
    const int* ei    = (const int*)d_in[1];
    const int* batch = (const int*)d_in[2];
    const float* mol = (const float*)d_in[3];
    const float* W1  = (const float*)d_in[4];  const float* b1  = (const float*)d_in[5];
    const float* g1  = (const float*)d_in[6];  const float* be1 = (const float*)d_in[7];
    const float* W2  = (const float*)d_in[8];  const float* b2  = (const float*)d_in[9];
    const float* g2  = (const float*)d_in[10]; const float* be2 = (const float*)d_in[11];
    const float* W3  = (const float*)d_in[12]; const float* b3  = (const float*)d_in[13];
    const float* Wf1 = (const float*)d_in[14]; const float* bf1 = (const float*)d_in[15];
    const float* Wf2 = (const float*)d_in[16]; const float* bf2 = (const float*)d_in[17];
    const int* srcv = ei;
    const int* dstv = ei + NE;
    float* out = (float*)d_out;

    char* p = (char*)d_ws;
    size_t off = 0;
    auto alloc = [&](size_t bytes) { void* q = p + off; off += (bytes + 255) & ~(size_t)255; return q; };
    float* buf0 = (float*)alloc((size_t)NN * DH * 4);
    float* buf1 = (float*)alloc((size_t)NN * DH * 4);
    int*   deg  = (int*)alloc((size_t)NN * 4);
    float* dinv = (float*)alloc((size_t)NN * 4);
    float* ssum = (float*)alloc(512);
    float* ssq  = (float*)alloc(512);
    float* scb  = (float*)alloc(512);
    float* shb  = (float*)alloc(512);
    float* hg   = (float*)alloc((size_t)NG * DH * 4);

    hipMemsetAsync(deg, 0, (size_t)NN * 4, stream);
    k_deg<<<(NE + 255) / 256, 256, 0, stream>>>(dstv, deg);
    k_dinv<<<(NN + 255) / 256, 256, 0, stream>>>(deg, dinv);

    const int GB = (NN + 63) / 64;
    const int EB = (NE + 3) / 4;

    // ---- Layer 1 ----
    k_gemm<0><<<GB, 256, 0, stream>>>(x, W1, nullptr, nullptr, dinv, buf0);
    hipMemsetAsync(buf1, 0, (size_t)NN * DH * 4, stream);
    k_edge<<<EB, 256, 0, stream>>>(buf0, srcv, dstv, buf1);
    hipMemsetAsync(ssum, 0, 512, stream);
    hipMemsetAsync(ssq, 0, 512, stream);
    k_post<0><<<512, 256, 0, stream>>>(buf0, buf1, dinv, b1, ssum, ssq, nullptr, nullptr);
    k_bnfin<<<1, 128, 0, stream>>>(ssum, ssq, g1, be1, scb, shb);

    // ---- Layer 2 (BN of h1 fused into GEMM staging; in-place GEMM) ----
    k_gemm<1><<<GB, 256, 0, stream>>>(buf1, W2, scb, shb, dinv, buf1);
    hipMemsetAsync(buf0, 0, (size_t)NN * DH * 4, stream);
    k_edge<<<EB, 256, 0, stream>>>(buf1, srcv, dstv, buf0);
    hipMemsetAsync(ssum, 0, 512, stream);
    hipMemsetAsync(ssq, 0, 512, stream);
    k_post<0><<<512, 256, 0, stream>>>(buf1, buf0, dinv, b2, ssum, ssq, nullptr, nullptr);
    k_bnfin<<<1, 128, 0, stream>>>(ssum, ssq, g2, be2, scb, shb);

    // ---- Layer 3 (no BN; pooling fused into post pass) ----
    k_gemm<1><<<GB, 256, 0, stream>>>(buf0, W3, scb, shb, dinv, buf0);
    hipMemsetAsync(buf1, 0, (size_t)NN * DH * 4, stream);
    k_edge<<<EB, 256, 0, stream>>>(buf0, srcv, dstv, buf1);
    hipMemsetAsync(hg, 0, (size_t)NG * DH * 4, stream);
    k_post<1><<<512, 256, 0, stream>>>(buf0, buf1, dinv, b3, nullptr, nullptr, batch, hg);

    k_mlp<<<NG, 128, 0, stream>>>(hg, mol, Wf1, bf1, Wf2, bf2, out);
}

// Round 3
// 1032.112 us; speedup vs baseline: 4.3462x; 4.3462x over previous
//
#include <hip/hip_runtime.h>

#define NN 100000      // nodes
#define NE 1600000     // edges
#define NG 2048        // graphs
#define DH 128         // feature dim
#define SCAN_B 391     // ceil(NN/256)

__device__ __forceinline__ float selu_f(float x) {
    return x > 0.f ? 1.0507009873554805f * x : 1.7580993408473766f * expm1f(x);
}

// ---------------- CSR build ----------------
__global__ __launch_bounds__(256) void k_deg(const int* __restrict__ dst, int* __restrict__ deg) {
    int e = blockIdx.x * 256 + threadIdx.x;
    if (e < NE) atomicAdd(deg + dst[e], 1);
}

__global__ __launch_bounds__(256) void k_dinv(const int* __restrict__ deg, float* __restrict__ dinv) {
    int i = blockIdx.x * 256 + threadIdx.x;
    if (i < NN) dinv[i] = rsqrtf((float)deg[i] + 1.0f);
}

// per-256-chunk local exclusive scan; psum[b] = chunk total
__global__ __launch_bounds__(256) void k_scan1(const int* __restrict__ deg,
                                               int* __restrict__ rp_local, int* __restrict__ psum) {
    __shared__ int tmp[256];
    int t = threadIdx.x;
    int i = blockIdx.x * 256 + t;
    int v = (i < NN) ? deg[i] : 0;
    tmp[t] = v; __syncthreads();
    #pragma unroll
    for (int o = 1; o < 256; o <<= 1) {
        int u = (t >= o) ? tmp[t - o] : 0; __syncthreads();
        tmp[t] += u; __syncthreads();
    }
    if (i < NN) rp_local[i] = tmp[t] - v;
    if (t == 255) psum[blockIdx.x] = tmp[t];
}

// scan the 391 partials (single block of 512)
__global__ __launch_bounds__(512) void k_scan2(int* __restrict__ psum, int* __restrict__ rowptr) {
    __shared__ int tmp[512];
    int t = threadIdx.x;
    int v = (t < SCAN_B) ? psum[t] : 0;
    tmp[t] = v; __syncthreads();
    #pragma unroll
    for (int o = 1; o < 512; o <<= 1) {
        int u = (t >= o) ? tmp[t - o] : 0; __syncthreads();
        tmp[t] += u; __syncthreads();
    }
    if (t < SCAN_B) psum[t] = tmp[t] - v;   // exclusive
    if (t == 0) rowptr[NN] = NE;
}

__global__ __launch_bounds__(256) void k_scan3(const int* __restrict__ rp_local, const int* __restrict__ psum,
                                               int* __restrict__ rowptr, int* __restrict__ wptr) {
    int i = blockIdx.x * 256 + threadIdx.x;
    if (i < NN) {
        int v = rp_local[i] + psum[blockIdx.x];
        rowptr[i] = v;
        wptr[i] = v;
    }
}

__global__ __launch_bounds__(256) void k_fill(const int* __restrict__ src, const int* __restrict__ dst,
                                              int* __restrict__ wptr, int* __restrict__ csr_src) {
    int e = blockIdx.x * 256 + threadIdx.x;
    if (e < NE) {
        int pos = atomicAdd(wptr + dst[e], 1);
        csr_src[pos] = src[e];
    }
}

// ---------------- GEMM:  X = (affine(H) @ W) * dinv[row] ----------------
template<int AFFINE>
__global__ __launch_bounds__(256) void k_gemm(
    const float* __restrict__ H, const float* __restrict__ W,
    const float* __restrict__ sc, const float* __restrict__ sh,
    const float* __restrict__ dinv, float* __restrict__ X)
{
    __shared__ float hs[64][132];
    __shared__ float ws[32][128];
    const int tid = threadIdx.x;
    const int base = blockIdx.x * 64;
    const int ct = tid & 15, rt = tid >> 4;
    const int r0 = rt * 4;
    const int cA = ct * 4, cB = cA + 64;

    #pragma unroll
    for (int i = 0; i < 8; ++i) {
        int idx4 = tid + i * 256;
        int r = idx4 >> 5;
        int c = (idx4 & 31) * 4;
        int row = base + r;
        float4 v = make_float4(0.f, 0.f, 0.f, 0.f);
        if (row < NN) v = *(const float4*)(H + (size_t)row * DH + c);
        if (AFFINE) {
            v.x = v.x * sc[c + 0] + sh[c + 0];
            v.y = v.y * sc[c + 1] + sh[c + 1];
            v.z = v.z * sc[c + 2] + sh[c + 2];
            v.w = v.w * sc[c + 3] + sh[c + 3];
        }
        *(float4*)&hs[r][c] = v;
    }

    float acc[4][8];
    #pragma unroll
    for (int i = 0; i < 4; ++i)
        #pragma unroll
        for (int j = 0; j < 8; ++j) acc[i][j] = 0.f;

    for (int kk = 0; kk < DH; kk += 32) {
        __syncthreads();
        #pragma unroll
        for (int i = 0; i < 4; ++i) {
            int idx4 = tid + i * 256;
            int k = idx4 >> 5;
            int c = (idx4 & 31) * 4;
            *(float4*)&ws[k][c] = *(const float4*)(W + (size_t)(kk + k) * DH + c);
        }
        __syncthreads();
        #pragma unroll
        for (int k = 0; k < 32; ++k) {
            float4 w0 = *(const float4*)&ws[k][cA];
            float4 w1 = *(const float4*)&ws[k][cB];
            #pragma unroll
            for (int i = 0; i < 4; ++i) {
                float h = hs[r0 + i][kk + k];
                acc[i][0] += h * w0.x; acc[i][1] += h * w0.y;
                acc[i][2] += h * w0.z; acc[i][3] += h * w0.w;
                acc[i][4] += h * w1.x; acc[i][5] += h * w1.y;
                acc[i][6] += h * w1.z; acc[i][7] += h * w1.w;
            }
        }
    }

    #pragma unroll
    for (int i = 0; i < 4; ++i) {
        int row = base + r0 + i;
        if (row < NN) {
            float di = dinv[row];
            float4 o0 = make_float4(acc[i][0] * di, acc[i][1] * di, acc[i][2] * di, acc[i][3] * di);
            float4 o1 = make_float4(acc[i][4] * di, acc[i][5] * di, acc[i][6] * di, acc[i][7] * di);
            *(float4*)(X + (size_t)row * DH + cA) = o0;
            *(float4*)(X + (size_t)row * DH + cB) = o1;
        }
    }
}

// -------- fused gather-aggregate + self-loop + bias + SELU --------
// One wave per node; lane owns channels (2l, 2l+1).
// Y[i] = selu(dinv[i] * (X[i] + sum_{j in row i} X[csr_src[j]]) + b)
__global__ __launch_bounds__(256) void k_agg(
    const float* __restrict__ X, const int* __restrict__ rowptr,
    const int* __restrict__ csr_src, const float* __restrict__ dinv,
    const float* __restrict__ bias, float* __restrict__ Y)
{
    int node = blockIdx.x * 4 + (threadIdx.x >> 6);
    if (node >= NN) return;
    int lane = threadIdx.x & 63;
    const float2* Xr = (const float2*)X;
    float2 a0 = Xr[(size_t)node * 64 + lane];     // self-loop term
    float2 a1 = make_float2(0.f, 0.f);
    int jb = rowptr[node], je = rowptr[node + 1];
    int j = jb;
    for (; j + 1 < je; j += 2) {
        int s0 = csr_src[j], s1 = csr_src[j + 1];
        float2 v0 = Xr[(size_t)s0 * 64 + lane];
        float2 v1 = Xr[(size_t)s1 * 64 + lane];
        a0.x += v0.x; a0.y += v0.y;
        a1.x += v1.x; a1.y += v1.y;
    }
    if (j < je) {
        int s0 = csr_src[j];
        float2 v0 = Xr[(size_t)s0 * 64 + lane];
        a0.x += v0.x; a0.y += v0.y;
    }
    float di = dinv[node];
    int c = lane * 2;
    float y0 = selu_f(di * (a0.x + a1.x) + bias[c]);
    float y1 = selu_f(di * (a0.y + a1.y) + bias[c + 1]);
    ((float2*)Y)[(size_t)node * 64 + lane] = make_float2(y0, y1);
}

// ---------------- BN stats over Y ----------------
__global__ __launch_bounds__(256) void k_stats(const float* __restrict__ Y,
                                               float* __restrict__ ssum, float* __restrict__ ssq)
{
    const int tid = threadIdx.x;
    float s = 0.f, s2 = 0.f;
    const int total = NN * DH;
    const int stride = gridDim.x * 256;
    for (int idx = blockIdx.x * 256 + tid; idx < total; idx += stride) {
        float y = Y[idx];
        s += y; s2 += y * y;
    }
    __shared__ float r1[256], r2[256];
    r1[tid] = s; r2[tid] = s2;
    __syncthreads();
    if (tid < 128) {
        unsafeAtomicAdd(ssum + tid, r1[tid] + r1[tid + 128]);
        unsafeAtomicAdd(ssq + tid, r2[tid] + r2[tid + 128]);
    }
}

__global__ void k_bnfin(const float* __restrict__ ssum, const float* __restrict__ ssq,
                        const float* __restrict__ gamma, const float* __restrict__ beta,
                        float* __restrict__ sc, float* __restrict__ sh)
{
    int c = threadIdx.x;
    float mean = ssum[c] * (1.f / NN);
    float var = ssq[c] * (1.f / NN) - mean * mean;
    float s = gamma[c] * rsqrtf(var + 1e-5f);
    sc[c] = s;
    sh[c] = beta[c] - mean * s;
}

// ---------------- pooling: batch is sorted -> per-graph segment sum ----------------
__global__ __launch_bounds__(128) void k_pool(const float* __restrict__ Y,
                                              const int* __restrict__ batch, float* __restrict__ hg)
{
    int g = blockIdx.x;
    __shared__ int bounds[2];
    if (threadIdx.x < 2) {
        int target = g + threadIdx.x;
        int lo = 0, hi = NN;
        while (lo < hi) { int mid = (lo + hi) >> 1; if (batch[mid] < target) lo = mid + 1; else hi = mid; }
        bounds[threadIdx.x] = lo;
    }
    __syncthreads();
    int s = bounds[0], e = bounds[1];
    int c = threadIdx.x;
    float acc = 0.f;
    for (int i = s; i < e; ++i) acc += Y[(size_t)i * DH + c];
    hg[(size_t)g * DH + c] = acc;
}

// ---------------- final MLP ----------------
__global__ __launch_bounds__(128) void k_mlp(
    const float* __restrict__ hg, const float* __restrict__ mol,
    const float* __restrict__ Wf1, const float* __restrict__ bf1,
    const float* __restrict__ Wf2, const float* __restrict__ bf2,
    float* __restrict__ out)
{
    int g = blockIdx.x, c = threadIdx.x;
    __shared__ float in_s[192];
    in_s[c] = hg[(size_t)g * DH + c];
    if (c < 64) in_s[128 + c] = mol[(size_t)g * 64 + c];
    __syncthreads();
    float acc = bf1[c];
    #pragma unroll 8
    for (int k = 0; k < 192; ++k) acc += in_s[k] * Wf1[k * DH + c];
    float h = selu_f(acc);
    float pv = h * Wf2[c];
    #pragma unroll
    for (int o = 32; o > 0; o >>= 1) pv += __shfl_down(pv, o);
    __shared__ float wsum[2];
    if ((c & 63) == 0) wsum[c >> 6] = pv;
    __syncthreads();
    if (c == 0) out[g] = wsum[0] + wsum[1] + bf2[0];
}

extern "C" void kernel_launch(void* const* d_in, const int* in_sizes, int n_in,
                              void* d_out, int out_size, void* d_ws, size_t ws_size,
                              hipStream_t stream)
{
    const float* x   = (const float*)d_in[0];
    const int* ei    = (const int*)d_in[1];
    const int* batch = (const int*)d_in[2];
    const float* mol = (const float*)d_in[3];
    const float* W1  = (const float*)d_in[4];  const float* b1  = (const float*)d_in[5];
    const float* g1  = (const float*)d_in[6];  const float* be1 = (const float*)d_in[7];
    const float* W2  = (const float*)d_in[8];  const float* b2  = (const float*)d_in[9];
    const float* g2  = (const float*)d_in[10]; const float* be2 = (const float*)d_in[11];
    const float* W3  = (const float*)d_in[12]; const float* b3  = (const float*)d_in[13];
    const float* Wf1 = (const float*)d_in[14]; const float* bf1 = (const float*)d_in[15];
    const float* Wf2 = (const float*)d_in[16]; const float* bf2 = (const float*)d_in[17];
    const int* srcv = ei;
    const int* dstv = ei + NE;
    float* out = (float*)d_out;

    char* p = (char*)d_ws;
    size_t off = 0;
    auto alloc = [&](size_t bytes) { void* q = p + off; off += (bytes + 255) & ~(size_t)255; return q; };
    float* buf0   = (float*)alloc((size_t)NN * DH * 4);
    float* buf1   = (float*)alloc((size_t)NN * DH * 4);
    int*   deg    = (int*)alloc((size_t)NN * 4);
    float* dinv   = (float*)alloc((size_t)NN * 4);
    int*   rowptr = (int*)alloc((size_t)(NN + 1) * 4);
    int*   wptr   = (int*)alloc((size_t)NN * 4);
    int*   rp_loc = (int*)alloc((size_t)NN * 4);
    int*   psum   = (int*)alloc((size_t)512 * 4);
    int*   csr    = (int*)alloc((size_t)NE * 4);
    float* ssum   = (float*)alloc(512);
    float* ssq    = (float*)alloc(512);
    float* scb    = (float*)alloc(512);
    float* shb    = (float*)alloc(512);
    float* hg     = (float*)alloc((size_t)NG * DH * 4);

    const int NB = (NN + 255) / 256;   // = SCAN_B
    const int EBt = (NE + 255) / 256;
    const int GB = (NN + 63) / 64;
    const int AB = (NN + 3) / 4;

    // ---- CSR build (amortized over 3 aggregations) ----
    hipMemsetAsync(deg, 0, (size_t)NN * 4, stream);
    k_deg<<<EBt, 256, 0, stream>>>(dstv, deg);
    k_dinv<<<NB, 256, 0, stream>>>(deg, dinv);
    k_scan1<<<NB, 256, 0, stream>>>(deg, rp_loc, psum);
    k_scan2<<<1, 512, 0, stream>>>(psum, rowptr);
    k_scan3<<<NB, 256, 0, stream>>>(rp_loc, psum, rowptr, wptr);
    k_fill<<<EBt, 256, 0, stream>>>(srcv, dstv, wptr, csr);

    // ---- Layer 1 ----
    k_gemm<0><<<GB, 256, 0, stream>>>(x, W1, nullptr, nullptr, dinv, buf0);
    k_agg<<<AB, 256, 0, stream>>>(buf0, rowptr, csr, dinv, b1, buf1);
    hipMemsetAsync(ssum, 0, 512, stream);
    hipMemsetAsync(ssq, 0, 512, stream);
    k_stats<<<512, 256, 0, stream>>>(buf1, ssum, ssq);
    k_bnfin<<<1, 128, 0, stream>>>(ssum, ssq, g1, be1, scb, shb);

    // ---- Layer 2 ----
    k_gemm<1><<<GB, 256, 0, stream>>>(buf1, W2, scb, shb, dinv, buf0);
    k_agg<<<AB, 256, 0, stream>>>(buf0, rowptr, csr, dinv, b2, buf1);
    hipMemsetAsync(ssum, 0, 512, stream);
    hipMemsetAsync(ssq, 0, 512, stream);
    k_stats<<<512, 256, 0, stream>>>(buf1, ssum, ssq);
    k_bnfin<<<1, 128, 0, stream>>>(ssum, ssq, g2, be2, scb, shb);

    // ---- Layer 3 ----
    k_gemm<1><<<GB, 256, 0, stream>>>(buf1, W3, scb, shb, dinv, buf0);
    k_agg<<<AB, 256, 0, stream>>>(buf0, rowptr, csr, dinv, b3, buf1);
    k_pool<<<NG, 128, 0, stream>>>(buf1, batch, hg);

    k_mlp<<<NG, 128, 0, stream>>>(hg, mol, Wf1, bf1, Wf2, bf2, out);
}

// Round 6
// 961.955 us; speedup vs baseline: 4.6632x; 1.0729x over previous
//
#include <hip/hip_runtime.h>

#define NN 100000      // nodes
#define NE 1600000     // edges
#define NG 2048        // graphs
#define DH 128         // feature dim
#define SCAN_B 391     // ceil(NN/256)

__device__ __forceinline__ float selu_f(float x) {
    return x > 0.f ? 1.0507009873554805f * x : 1.7580993408473766f * expm1f(x);
}

// ---------------- CSR build ----------------
__global__ __launch_bounds__(256) void k_deg(const int* __restrict__ dst, int* __restrict__ deg) {
    int e = blockIdx.x * 256 + threadIdx.x;
    if (e < NE) atomicAdd(deg + dst[e], 1);
}

__global__ __launch_bounds__(256) void k_dinv(const int* __restrict__ deg, float* __restrict__ dinv) {
    int i = blockIdx.x * 256 + threadIdx.x;
    if (i < NN) dinv[i] = rsqrtf((float)deg[i] + 1.0f);
}

// per-256-chunk local exclusive scan; psum[b] = chunk total
__global__ __launch_bounds__(256) void k_scan1(const int* __restrict__ deg,
                                               int* __restrict__ rp_local, int* __restrict__ psum) {
    __shared__ int tmp[256];
    int t = threadIdx.x;
    int i = blockIdx.x * 256 + t;
    int v = (i < NN) ? deg[i] : 0;
    tmp[t] = v; __syncthreads();
    #pragma unroll
    for (int o = 1; o < 256; o <<= 1) {
        int u = (t >= o) ? tmp[t - o] : 0; __syncthreads();
        tmp[t] += u; __syncthreads();
    }
    if (i < NN) rp_local[i] = tmp[t] - v;
    if (t == 255) psum[blockIdx.x] = tmp[t];
}

// scan the 391 partials (single block of 512)
__global__ __launch_bounds__(512) void k_scan2(int* __restrict__ psum, int* __restrict__ rowptr) {
    __shared__ int tmp[512];
    int t = threadIdx.x;
    int v = (t < SCAN_B) ? psum[t] : 0;
    tmp[t] = v; __syncthreads();
    #pragma unroll
    for (int o = 1; o < 512; o <<= 1) {
        int u = (t >= o) ? tmp[t - o] : 0; __syncthreads();
        tmp[t] += u; __syncthreads();
    }
    if (t < SCAN_B) psum[t] = tmp[t] - v;   // exclusive
    if (t == 0) rowptr[NN] = NE;
}

__global__ __launch_bounds__(256) void k_scan3(const int* __restrict__ rp_local, const int* __restrict__ psum,
                                               int* __restrict__ rowptr, int* __restrict__ wptr) {
    int i = blockIdx.x * 256 + threadIdx.x;
    if (i < NN) {
        int v = rp_local[i] + psum[blockIdx.x];
        rowptr[i] = v;
        wptr[i] = v;
    }
}

__global__ __launch_bounds__(256) void k_fill(const int* __restrict__ src, const int* __restrict__ dst,
                                              int* __restrict__ wptr, int* __restrict__ csr_src) {
    int e = blockIdx.x * 256 + threadIdx.x;
    if (e < NE) {
        int pos = atomicAdd(wptr + dst[e], 1);
        csr_src[pos] = src[e];
    }
}

// ---------------- GEMM:  X = (affine(H) @ W) * dinv[row] ----------------
template<int AFFINE>
__global__ __launch_bounds__(256) void k_gemm(
    const float* __restrict__ H, const float* __restrict__ W,
    const float* __restrict__ sc, const float* __restrict__ sh,
    const float* __restrict__ dinv, float* __restrict__ X)
{
    __shared__ float hs[64][132];
    __shared__ float ws[32][128];
    const int tid = threadIdx.x;
    const int base = blockIdx.x * 64;
    const int ct = tid & 15, rt = tid >> 4;
    const int r0 = rt * 4;
    const int cA = ct * 4, cB = cA + 64;

    #pragma unroll
    for (int i = 0; i < 8; ++i) {
        int idx4 = tid + i * 256;
        int r = idx4 >> 5;
        int c = (idx4 & 31) * 4;
        int row = base + r;
        float4 v = make_float4(0.f, 0.f, 0.f, 0.f);
        if (row < NN) v = *(const float4*)(H + (size_t)row * DH + c);
        if (AFFINE) {
            v.x = v.x * sc[c + 0] + sh[c + 0];
            v.y = v.y * sc[c + 1] + sh[c + 1];
            v.z = v.z * sc[c + 2] + sh[c + 2];
            v.w = v.w * sc[c + 3] + sh[c + 3];
        }
        *(float4*)&hs[r][c] = v;
    }

    float acc[4][8];
    #pragma unroll
    for (int i = 0; i < 4; ++i)
        #pragma unroll
        for (int j = 0; j < 8; ++j) acc[i][j] = 0.f;

    for (int kk = 0; kk < DH; kk += 32) {
        __syncthreads();
        #pragma unroll
        for (int i = 0; i < 4; ++i) {
            int idx4 = tid + i * 256;
            int k = idx4 >> 5;
            int c = (idx4 & 31) * 4;
            *(float4*)&ws[k][c] = *(const float4*)(W + (size_t)(kk + k) * DH + c);
        }
        __syncthreads();
        #pragma unroll
        for (int k = 0; k < 32; ++k) {
            float4 w0 = *(const float4*)&ws[k][cA];
            float4 w1 = *(const float4*)&ws[k][cB];
            #pragma unroll
            for (int i = 0; i < 4; ++i) {
                float h = hs[r0 + i][kk + k];
                acc[i][0] += h * w0.x; acc[i][1] += h * w0.y;
                acc[i][2] += h * w0.z; acc[i][3] += h * w0.w;
                acc[i][4] += h * w1.x; acc[i][5] += h * w1.y;
                acc[i][6] += h * w1.z; acc[i][7] += h * w1.w;
            }
        }
    }

    #pragma unroll
    for (int i = 0; i < 4; ++i) {
        int row = base + r0 + i;
        if (row < NN) {
            float di = dinv[row];
            float4 o0 = make_float4(acc[i][0] * di, acc[i][1] * di, acc[i][2] * di, acc[i][3] * di);
            float4 o1 = make_float4(acc[i][4] * di, acc[i][5] * di, acc[i][6] * di, acc[i][7] * di);
            *(float4*)(X + (size_t)row * DH + cA) = o0;
            *(float4*)(X + (size_t)row * DH + cB) = o1;
        }
    }
}

// -------- fused gather-aggregate + self-loop + bias + SELU --------
// One wave per node.  Indices for the whole row are loaded ONCE (coalesced,
// one per lane) and broadcast via shfl — no VMEM index load inside the gather
// loop.  Each lane loads float4 (16B); half-wave covers a 512B row, so one
// 64-lane VMEM instruction gathers TWO edges.  4 edges per iteration.
__global__ __launch_bounds__(256) void k_agg(
    const float* __restrict__ X, const int* __restrict__ rowptr,
    const int* __restrict__ csr_src, const float* __restrict__ dinv,
    const float* __restrict__ bias, float* __restrict__ Y)
{
    int node = blockIdx.x * 4 + (threadIdx.x >> 6);
    if (node >= NN) return;
    const int lane = threadIdx.x & 63;
    const int half = lane >> 5;        // which edge of the pair this lane serves
    const int qc = lane & 31;          // float4 index within row (channels qc*4..qc*4+3)
    const float4* __restrict__ X4 = (const float4*)X;   // row stride 32

    float4 acc = make_float4(0.f, 0.f, 0.f, 0.f);
    const int jb = rowptr[node], je = rowptr[node + 1];
    const int cnt = je - jb;

    for (int base = 0; base < cnt; base += 64) {
        int m = cnt - base; if (m > 64) m = 64;
        // one coalesced index load per wave per batch; OOB lanes -> 0 (safe gather, weight-killed)
        int idx_l = (base + lane < cnt) ? csr_src[jb + base + lane] : 0;
        for (int t = 0; t < m; t += 4) {
            int eA = t + half;
            int eB = t + 2 + half;
            int iA = __shfl(idx_l, eA);
            int iB = __shfl(idx_l, eB);
            float wA = (eA < m) ? 1.f : 0.f;
            float wB = (eB < m) ? 1.f : 0.f;
            float4 vA = X4[(size_t)iA * 32 + qc];
            float4 vB = X4[(size_t)iB * 32 + qc];
            acc.x += wA * vA.x; acc.y += wA * vA.y; acc.z += wA * vA.z; acc.w += wA * vA.w;
            acc.x += wB * vB.x; acc.y += wB * vB.y; acc.z += wB * vB.z; acc.w += wB * vB.w;
        }
    }

    // combine the two half-wave partial sums (same channels in lanes l and l^32)
    acc.x += __shfl_xor(acc.x, 32);
    acc.y += __shfl_xor(acc.y, 32);
    acc.z += __shfl_xor(acc.z, 32);
    acc.w += __shfl_xor(acc.w, 32);

    if (half == 0) {
        float4 self = X4[(size_t)node * 32 + qc];
        float di = dinv[node];
        float4 bv = ((const float4*)bias)[qc];
        float4 o;
        o.x = selu_f(di * (acc.x + self.x) + bv.x);
        o.y = selu_f(di * (acc.y + self.y) + bv.y);
        o.z = selu_f(di * (acc.z + self.z) + bv.z);
        o.w = selu_f(di * (acc.w + self.w) + bv.w);
        ((float4*)Y)[(size_t)node * 32 + qc] = o;
    }
}

// ---------------- BN stats over Y ----------------
__global__ __launch_bounds__(256) void k_stats(const float* __restrict__ Y,
                                               float* __restrict__ ssum, float* __restrict__ ssq)
{
    const int tid = threadIdx.x;
    float s = 0.f, s2 = 0.f;
    const int total = NN * DH;
    const int stride = gridDim.x * 256;
    for (int idx = blockIdx.x * 256 + tid; idx < total; idx += stride) {
        float y = Y[idx];
        s += y; s2 += y * y;
    }
    __shared__ float r1[256], r2[256];
    r1[tid] = s; r2[tid] = s2;
    __syncthreads();
    if (tid < 128) {
        unsafeAtomicAdd(ssum + tid, r1[tid] + r1[tid + 128]);
        unsafeAtomicAdd(ssq + tid, r2[tid] + r2[tid + 128]);
    }
}

__global__ void k_bnfin(const float* __restrict__ ssum, const float* __restrict__ ssq,
                        const float* __restrict__ gamma, const float* __restrict__ beta,
                        float* __restrict__ sc, float* __restrict__ sh)
{
    int c = threadIdx.x;
    float mean = ssum[c] * (1.f / NN);
    float var = ssq[c] * (1.f / NN) - mean * mean;
    float s = gamma[c] * rsqrtf(var + 1e-5f);
    sc[c] = s;
    sh[c] = beta[c] - mean * s;
}

// ---------------- pooling: batch is sorted -> per-graph segment sum ----------------
__global__ __launch_bounds__(128) void k_pool(const float* __restrict__ Y,
                                              const int* __restrict__ batch, float* __restrict__ hg)
{
    int g = blockIdx.x;
    __shared__ int bounds[2];
    if (threadIdx.x < 2) {
        int target = g + threadIdx.x;
        int lo = 0, hi = NN;
        while (lo < hi) { int mid = (lo + hi) >> 1; if (batch[mid] < target) lo = mid + 1; else hi = mid; }
        bounds[threadIdx.x] = lo;
    }
    __syncthreads();
    int s = bounds[0], e = bounds[1];
    int c = threadIdx.x;
    float acc = 0.f;
    for (int i = s; i < e; ++i) acc += Y[(size_t)i * DH + c];
    hg[(size_t)g * DH + c] = acc;
}

// ---------------- final MLP ----------------
__global__ __launch_bounds__(128) void k_mlp(
    const float* __restrict__ hg, const float* __restrict__ mol,
    const float* __restrict__ Wf1, const float* __restrict__ bf1,
    const float* __restrict__ Wf2, const float* __restrict__ bf2,
    float* __restrict__ out)
{
    int g = blockIdx.x, c = threadIdx.x;
    __shared__ float in_s[192];
    in_s[c] = hg[(size_t)g * DH + c];
    if (c < 64) in_s[128 + c] = mol[(size_t)g * 64 + c];
    __syncthreads();
    float acc = bf1[c];
    #pragma unroll 8
    for (int k = 0; k < 192; ++k) acc += in_s[k] * Wf1[k * DH + c];
    float h = selu_f(acc);
    float pv = h * Wf2[c];
    #pragma unroll
    for (int o = 32; o > 0; o >>= 1) pv += __shfl_down(pv, o);
    __shared__ float wsum[2];
    if ((c & 63) == 0) wsum[c >> 6] = pv;
    __syncthreads();
    if (c == 0) out[g] = wsum[0] + wsum[1] + bf2[0];
}

extern "C" void kernel_launch(void* const* d_in, const int* in_sizes, int n_in,
                              void* d_out, int out_size, void* d_ws, size_t ws_size,
                              hipStream_t stream)
{
    const float* x   = (const float*)d_in[0];
    const int* ei    = (const int*)d_in[1];
    const int* batch = (const int*)d_in[2];
    const float* mol = (const float*)d_in[3];
    const float* W1  = (const float*)d_in[4];  const float* b1  = (const float*)d_in[5];
    const float* g1  = (const float*)d_in[6];  const float* be1 = (const float*)d_in[7];
    const float* W2  = (const float*)d_in[8];  const float* b2  = (const float*)d_in[9];
    const float* g2  = (const float*)d_in[10]; const float* be2 = (const float*)d_in[11];
    const float* W3  = (const float*)d_in[12]; const float* b3  = (const float*)d_in[13];
    const float* Wf1 = (const float*)d_in[14]; const float* bf1 = (const float*)d_in[15];
    const float* Wf2 = (const float*)d_in[16]; const float* bf2 = (const float*)d_in[17];
    const int* srcv = ei;
    const int* dstv = ei + NE;
    float* out = (float*)d_out;

    char* p = (char*)d_ws;
    size_t off = 0;
    auto alloc = [&](size_t bytes) { void* q = p + off; off += (bytes + 255) & ~(size_t)255; return q; };
    float* buf0   = (float*)alloc((size_t)NN * DH * 4);
    float* buf1   = (float*)alloc((size_t)NN * DH * 4);
    int*   deg    = (int*)alloc((size_t)NN * 4);
    float* dinv   = (float*)alloc((size_t)NN * 4);
    int*   rowptr = (int*)alloc((size_t)(NN + 1) * 4);
    int*   wptr   = (int*)alloc((size_t)NN * 4);
    int*   rp_loc = (int*)alloc((size_t)NN * 4);
    int*   psum   = (int*)alloc((size_t)512 * 4);
    int*   csr    = (int*)alloc((size_t)NE * 4);
    float* ssum   = (float*)alloc(512);
    float* ssq    = (float*)alloc(512);
    float* scb    = (float*)alloc(512);
    float* shb    = (float*)alloc(512);
    float* hg     = (float*)alloc((size_t)NG * DH * 4);

    const int NB = (NN + 255) / 256;   // = SCAN_B
    const int EBt = (NE + 255) / 256;
    const int GB = (NN + 63) / 64;
    const int AB = (NN + 3) / 4;

    // ---- CSR build (amortized over 3 aggregations) ----
    hipMemsetAsync(deg, 0, (size_t)NN * 4, stream);
    k_deg<<<EBt, 256, 0, stream>>>(dstv, deg);
    k_dinv<<<NB, 256, 0, stream>>>(deg, dinv);
    k_scan1<<<NB, 256, 0, stream>>>(deg, rp_loc, psum);
    k_scan2<<<1, 512, 0, stream>>>(psum, rowptr);
    k_scan3<<<NB, 256, 0, stream>>>(rp_loc, psum, rowptr, wptr);
    k_fill<<<EBt, 256, 0, stream>>>(srcv, dstv, wptr, csr);

    // ---- Layer 1 ----
    k_gemm<0><<<GB, 256, 0, stream>>>(x, W1, nullptr, nullptr, dinv, buf0);
    k_agg<<<AB, 256, 0, stream>>>(buf0, rowptr, csr, dinv, b1, buf1);
    hipMemsetAsync(ssum, 0, 512, stream);
    hipMemsetAsync(ssq, 0, 512, stream);
    k_stats<<<512, 256, 0, stream>>>(buf1, ssum, ssq);
    k_bnfin<<<1, 128, 0, stream>>>(ssum, ssq, g1, be1, scb, shb);

    // ---- Layer 2 ----
    k_gemm<1><<<GB, 256, 0, stream>>>(buf1, W2, scb, shb, dinv, buf0);
    k_agg<<<AB, 256, 0, stream>>>(buf0, rowptr, csr, dinv, b2, buf1);
    hipMemsetAsync(ssum, 0, 512, stream);
    hipMemsetAsync(ssq, 0, 512, stream);
    k_stats<<<512, 256, 0, stream>>>(buf1, ssum, ssq);
    k_bnfin<<<1, 128, 0, stream>>>(ssum, ssq, g2, be2, scb, shb);

    // ---- Layer 3 ----
    k_gemm<1><<<GB, 256, 0, stream>>>(buf1, W3, scb, shb, dinv, buf0);
    k_agg<<<AB, 256, 0, stream>>>(buf0, rowptr, csr, dinv, b3, buf1);
    k_pool<<<NG, 128, 0, stream>>>(buf1, batch, hg);

    k_mlp<<<NG, 128, 0, stream>>>(hg, mol, Wf1, bf1, Wf2, bf2, out);
}